// Round 13
// baseline (309.070 us; speedup 1.0000x reference)
//
#include <hip/hip_runtime.h>
#include <hip/hip_cooperative_groups.h>

namespace cg = cooperative_groups;

#define N_NODES 50000
#define N_EDGES 800000
#define D 128
#define CAP 48      // bucket capacity per dst node (max in-degree ~45 for this dataset)
#define OVF_CAP 4096

#define NPART 256   // dst partitions == scatter blocks (coop grid size)
#define PN 196      // nodes per partition; 256*196 = 50176 >= 50000
#define NPAD (NPART * PN)
#define NCH 128     // edge chunks (hist/place active blocks)
#define CH ((N_EDGES + NCH - 1) / NCH)   // 6250 edges per chunk
#define NW (N_NODES / 4)                 // packed byte-counter words = 12500
#define WPB ((NW + NCH - 1) / NCH)       // cnt_s words per place block = 98

typedef unsigned short bf16_t;
typedef __attribute__((ext_vector_type(8))) short short8v;   // 8 bf16 = 4 VGPR (MFMA A/B frag)
typedef __attribute__((ext_vector_type(4))) float f32x4;     // MFMA C/D frag

__device__ inline float bf2f(bf16_t u) {
    union { unsigned int i; float f; } v;
    v.i = ((unsigned int)u) << 16;
    return v.f;
}
__device__ inline bf16_t f2bf(float f) {
    union { float f; unsigned int i; } v;
    v.f = f;
    unsigned int u = v.i;
    unsigned int r = (u + 0x7FFFu + ((u >> 16) & 1u)) >> 16;  // RNE
    return (bf16_t)r;
}
// bf16 pair packed in a u32 (little-endian: lo half = even col, hi half = odd col)
__device__ inline float u2f_lo(unsigned int u) {
    union { unsigned int i; float f; } x; x.i = u << 16; return x.f;
}
__device__ inline float u2f_hi(unsigned int u) {
    union { unsigned int i; float f; } x; x.i = u & 0xFFFF0000u; return x.f;
}

// =============== cooperative preprocessing mega-kernel ===============
// r12 evidence: 6 preprocessing dispatches = ~116 us wall for ~60-70 us of
// kernel exec (launch gaps + <=25%-CU grids). One cooperative kernel with
// grid.sync() between phases removes the gaps and runs every phase on the
// full machine. Phases:
//  A: wsplit (blocks 0-3) + 256-bin dst hist + src SWAR hist (blocks < 128)
//  B: per-bin parallel scan (all 256 blocks, one bin each)
//  C: place edges into bins (blocks < 128) + parallel cnt_s reduce
//  D: per-bin LDS bucket build + dense writeout + prescale (all 256 blocks)
struct HistSh { unsigned int hs[NW]; unsigned int hb[NPART]; };           // 51 KB
struct ScanSh { unsigned int sc[NCH]; };
struct PlaceSh { unsigned int cur[NPART]; unsigned int bb[NPART];
                 unsigned int red[WPB][17]; };                             // 8.7 KB
struct ScatSh { unsigned short bk[PN * CAP]; unsigned int cur[PN];
                unsigned int bb[NPART]; };                                 // 21.6 KB
union PreU { HistSh h; ScanSh s; PlaceSh p; ScatSh c; };

__global__ __launch_bounds__(1024) void preproc_kernel(
    const float* __restrict__ x, const int* __restrict__ src, const int* __restrict__ dst,
    const float* __restrict__ W1, const float* __restrict__ W2,
    bf16_t* __restrict__ Wf1, bf16_t* __restrict__ Wf2,
    unsigned int* __restrict__ H, unsigned int* __restrict__ OFF,
    unsigned int* __restrict__ binTot, unsigned int* __restrict__ binned,
    unsigned int* __restrict__ SH, int* __restrict__ cnt_s, int* __restrict__ cnt_d,
    unsigned short* __restrict__ bucket, int* __restrict__ ovf_cnt, int2* __restrict__ ovf,
    float* __restrict__ rs_out, float* __restrict__ rs_in, ushort4* __restrict__ xs4) {
    cg::grid_group grid = cg::this_grid();
    __shared__ PreU U;
    const int t = (int)threadIdx.x;
    const int b = (int)blockIdx.x;

    // ---------------- phase A: wsplit + hist ----------------
    if (b == 0 && t == 0) *ovf_cnt = 0;
    if (b < 4) {
        int fg = b * 1024 + t;                 // 0..4095: 2048 frags x 2 layers
        const float* W = (fg >= 2048) ? W2 : W1;
        bf16_t* Wf = (fg >= 2048) ? Wf2 : Wf1;
        int flat = fg & 2047;
        int lane = flat & 63;
        int c = (flat >> 6) & 7;
        int ks = flat >> 9;
        int n = c * 16 + (lane & 15);
        int kb = ks * 32 + (lane >> 4) * 8;
#pragma unroll
        for (int j = 0; j < 8; j++) {
            float w = W[(size_t)(kb + j) * D + n];
            bf16_t hi = f2bf(w);
            bf16_t lo = f2bf(w - bf2f(hi));
            Wf[(size_t)flat * 8 + j] = hi;
            Wf[(size_t)(2048 + flat) * 8 + j] = lo;
        }
    }
    if (b < NCH) {
        for (int i = t; i < NW; i += 1024) U.h.hs[i] = 0u;
        for (int i = t; i < NPART; i += 1024) U.h.hb[i] = 0u;
        __syncthreads();
        int e0 = b * CH;
        int e1 = min(e0 + CH, N_EDGES);
        for (int e = e0 + t; e < e1; e += 1024) {
            int s = src[e];
            int d = dst[e];
            atomicAdd(&U.h.hs[s >> 2], 1u << (8 * (s & 3)));  // per-chunk count < 256
            atomicAdd(&U.h.hb[d / PN], 1u);
        }
        __syncthreads();
        for (int i = t; i < NPART; i += 1024) H[(size_t)b * NPART + i] = U.h.hb[i];
        unsigned int* SHb = SH + (size_t)b * NW;
        for (int i = t; i < NW; i += 1024) SHb[i] = U.h.hs[i];
    }
    grid.sync();

    // ---------------- phase B: per-bin scan over NCH chunks (bin = b) ----------------
    unsigned int own = 0;
    if (t < NCH) {
        own = H[(size_t)t * NPART + b];
        U.s.sc[t] = own;
    }
    __syncthreads();
    for (int off = 1; off < NCH; off <<= 1) {
        unsigned int v = (t < NCH && t >= off) ? U.s.sc[t - off] : 0u;
        __syncthreads();
        if (t < NCH) U.s.sc[t] += v;
        __syncthreads();
    }
    if (t < NCH) OFF[(size_t)t * NPART + b] = U.s.sc[t] - own;   // exclusive within bin
    if (t == NCH - 1) binTot[b] = U.s.sc[t];
    grid.sync();

    // ---------------- phase C: place + cnt_s reduce (blocks < NCH) ----------------
    if (b < NCH) {
        if (t < NPART) U.p.bb[t] = binTot[t];
        __syncthreads();
        for (int off = 1; off < NPART; off <<= 1) {
            unsigned int v = (t < NPART && t >= off) ? U.p.bb[t - off] : 0u;
            __syncthreads();
            if (t < NPART) U.p.bb[t] += v;
            __syncthreads();
        }
        if (t < NPART) U.p.cur[t] = OFF[(size_t)b * NPART + t] + U.p.bb[t] - binTot[t];
        __syncthreads();
        int e0 = b * CH;
        int e1 = min(e0 + CH, N_EDGES);
        for (int e = e0 + t; e < e1; e += 1024) {
            int s = src[e];
            int d = dst[e];
            int bin = d / PN;
            unsigned int pos = atomicAdd(&U.p.cur[bin], 1u);
            binned[pos] = (unsigned int)(d - bin * PN) | ((unsigned int)s << 8);
        }
        // cnt_s: 16-way chunk-split reduce of SH, then tree-combine in LDS
        int wl = t >> 4;        // 0..63 (< WPB=98? no: only wl<64; need second pass)
        int cgp = t & 15;       // chunk group: 8 chunks each
        for (int base = 0; base < WPB; base += 64) {
            int wli = base + wl;
            if (wli < WPB) {
                int w = b * WPB + wli;
                if (w < NW) {
                    unsigned int run = 0;
#pragma unroll
                    for (int q = cgp * 8; q < cgp * 8 + 8; q++)
                        run += SH[(size_t)q * NW + w];   // SWAR
                    U.p.red[wli][cgp] = run;
                }
            }
        }
        __syncthreads();
        for (int wli = t; wli < WPB; wli += 1024) {
            int w = b * WPB + wli;
            if (w < NW) {
                unsigned int run = 0;
#pragma unroll
                for (int q = 0; q < 16; q++) run += U.p.red[wli][q];
                int4 c4;
                c4.x = (int)(run & 0xFFu); c4.y = (int)((run >> 8) & 0xFFu);
                c4.z = (int)((run >> 16) & 0xFFu); c4.w = (int)(run >> 24);
                ((int4*)cnt_s)[w] = c4;
            }
        }
    }
    grid.sync();

    // ---------------- phase D: scatter (bin = b) + prescale ----------------
    if (t < NPART) U.c.bb[t] = binTot[t];
    __syncthreads();
    for (int off = 1; off < NPART; off <<= 1) {
        unsigned int v = (t < NPART && t >= off) ? U.c.bb[t - off] : 0u;
        __syncthreads();
        if (t < NPART) U.c.bb[t] += v;
        __syncthreads();
    }
    unsigned int nB = binTot[b];
    unsigned int base = U.c.bb[b] - nB;   // exclusive base of bin b
    for (int i = t; i < PN; i += 1024) U.c.cur[i] = 0u;
    __syncthreads();
    const int nbeg = b * PN;
    for (unsigned int i = t; i < nB; i += 1024) {
        unsigned int v = binned[base + i];
        unsigned int dl = v & 0xFFu;
        unsigned int s = v >> 8;
        unsigned int q = atomicAdd(&U.c.cur[dl], 1u);
        if (q < CAP) {
            U.c.bk[dl * CAP + q] = (unsigned short)s;
        } else {
            int o = atomicAdd(ovf_cnt, 1);
            if (o < OVF_CAP) ovf[o] = make_int2(nbeg + (int)dl, (int)s);
        }
    }
    __syncthreads();
    // dense writeout: bucket region (PN*CAP*2 = 18816 B = 1176 uint4) + cnt_d
    {
        uint4* gb = (uint4*)(bucket + (size_t)nbeg * CAP);
        const uint4* lb = (const uint4*)U.c.bk;
        for (int i = t; i < PN * CAP * 2 / 16; i += 1024) gb[i] = lb[i];
        for (int i = t; i < PN; i += 1024) {
            int nd = nbeg + i;
            if (nd < N_NODES) cnt_d[nd] = (int)U.c.cur[i];
        }
    }
    // prescale for this partition's nodes (cnt_d from LDS, cnt_s global)
    for (int u = t; u < PN * 32; u += 1024) {
        int ln = u >> 5;
        int c = u & 31;
        int node = nbeg + ln;
        if (node < N_NODES) {
            float rs_o = rsqrtf(fmaxf((float)cnt_s[node], 1.0f));
            if (c == 0) {
                rs_out[node] = rs_o;
                rs_in[node] = rsqrtf(fmaxf((float)U.c.cur[ln], 1.0f));
            }
            float4 v = ((const float4*)x)[(size_t)node * 32 + c];
            ushort4 o;
            o.x = f2bf(v.x * rs_o);
            o.y = f2bf(v.y * rs_o);
            o.z = f2bf(v.z * rs_o);
            o.w = f2bf(v.w * rs_o);
            xs4[(size_t)node * 32 + c] = o;
        }
    }
}

// =============== fused gather + ovf-patch + MFMA gemm, 512 threads (EXACT r9 body) ===============
#define LDW 132
template <bool RELU_OUTSCALE, bool OUT_BF16>
__global__ __launch_bounds__(512) void fused_layer_kernel(
    const uint4* __restrict__ xsrc,          // bf16 row-major src features: 16 uint4/row
    const int* __restrict__ cnt_d,
    const unsigned short* __restrict__ bucket,
    const int* __restrict__ ovf_cnt, const int2* __restrict__ ovf,
    const float* __restrict__ rs_in, const float* __restrict__ rs_out,
    const bf16_t* __restrict__ Wf, const float* __restrict__ bias,
    void* __restrict__ outp, int nN) {
    __shared__ float sA[64 * LDW];   // 33.8 KB
    int tid = (int)threadIdx.x;
    int n0 = blockIdx.x * 64;
    int lane16 = tid & 15;
    int grp = tid >> 4;        // 0..31

    // ---- phase 1: gather 64 node rows into sA (2 rows/thread) ----
#define ACC8(v)                                              \
    a[0] += u2f_lo(v.x); a[1] += u2f_hi(v.x);                \
    a[2] += u2f_lo(v.y); a[3] += u2f_hi(v.y);                \
    a[4] += u2f_lo(v.z); a[5] += u2f_hi(v.z);                \
    a[6] += u2f_lo(v.w); a[7] += u2f_hi(v.w);
#pragma unroll
    for (int r = 0; r < 2; r++) {
        int ln = r * 32 + grp;     // local node 0..63
        int node = n0 + ln;
        float a[8];
#pragma unroll
        for (int k = 0; k < 8; k++) a[k] = 0.f;
        if (node < nN) {
            const unsigned short* bk = bucket + (size_t)node * CAP;
            int cnt = min(cnt_d[node], CAP);
            int e = 0;
            for (; e + 3 < cnt; e += 4) {
                int s0 = bk[e], s1 = bk[e + 1], s2 = bk[e + 2], s3 = bk[e + 3];
                uint4 v0 = xsrc[(size_t)s0 * 16 + lane16];
                uint4 v1 = xsrc[(size_t)s1 * 16 + lane16];
                uint4 v2 = xsrc[(size_t)s2 * 16 + lane16];
                uint4 v3 = xsrc[(size_t)s3 * 16 + lane16];
                ACC8(v0) ACC8(v1) ACC8(v2) ACC8(v3)
            }
            for (; e < cnt; e++) {
                int s0 = bk[e];
                uint4 v0 = xsrc[(size_t)s0 * 16 + lane16];
                ACC8(v0)
            }
        }
        float* row = sA + ln * LDW + lane16 * 8;
#pragma unroll
        for (int k = 0; k < 8; k++) row[k] = a[k];
    }
#undef ACC8

    // ---- overflow patch (uniform branch; no-op when list empty) ----
    int novf = min(*ovf_cnt, OVF_CAP);
    if (novf > 0) {
        __syncthreads();
        for (int i = tid; i < novf; i += 512) {
            int2 ds = ovf[i];
            int ln = ds.x - n0;
            if ((unsigned)ln < 64u) {
                const uint4* xr = xsrc + (size_t)ds.y * 16;
                for (int c = 0; c < 16; c++) {
                    uint4 v = xr[c];
                    float* q = sA + ln * LDW + c * 8;
                    atomicAdd(q + 0, u2f_lo(v.x)); atomicAdd(q + 1, u2f_hi(v.x));
                    atomicAdd(q + 2, u2f_lo(v.y)); atomicAdd(q + 3, u2f_hi(v.y));
                    atomicAdd(q + 4, u2f_lo(v.z)); atomicAdd(q + 5, u2f_hi(v.z));
                    atomicAdd(q + 6, u2f_lo(v.w)); atomicAdd(q + 7, u2f_hi(v.w));
                }
            }
        }
    }
    __syncthreads();

    // ---- phase 2: split-bf16 MFMA from LDS; wave pair per 16-node tile ----
    int lane = tid & 63;
    int wave = tid >> 6;       // 0..7
    int tile = wave >> 1;      // 0..3: node tile
    int half = wave & 1;       // 0..1: column half (64 cols)
    int ar = lane & 15;        // A row within tile
    int kg = lane >> 4;        // k-subchunk of 8
    const float* ap = sA + (tile * 16 + ar) * LDW + kg * 8;
    short8v ahi[4], alo[4];
#pragma unroll
    for (int ks = 0; ks < 4; ks++) {
#pragma unroll
        for (int j = 0; j < 8; j++) {
            float av = ap[ks * 32 + j];
            bf16_t h = f2bf(av);
            ahi[ks][j] = (short)h;
            alo[ks][j] = (short)f2bf(av - bf2f(h));
        }
    }

    f32x4 acc[4];
#pragma unroll
    for (int c = 0; c < 4; c++) acc[c] = (f32x4){0.f, 0.f, 0.f, 0.f};

    const short8v* Bh = (const short8v*)Wf;        // 2048 hi frags
    const short8v* Bl = Bh + 2048;                 // 2048 lo frags
#pragma unroll
    for (int ks = 0; ks < 4; ks++) {
#pragma unroll
        for (int c = 0; c < 4; c++) {
            int off = (ks * 8 + half * 4 + c) * 64 + lane;
            short8v wh = Bh[off];
            short8v wl = Bl[off];
            acc[c] = __builtin_amdgcn_mfma_f32_16x16x32_bf16(ahi[ks], wh, acc[c], 0, 0, 0);
            acc[c] = __builtin_amdgcn_mfma_f32_16x16x32_bf16(alo[ks], wh, acc[c], 0, 0, 0);
            acc[c] = __builtin_amdgcn_mfma_f32_16x16x32_bf16(ahi[ks], wl, acc[c], 0, 0, 0);
        }
    }

    // ---- epilogue: col = half*64 + c*16 + (lane&15), node = n0 + tile*16 + kg*4 + r ----
    int ocol = lane & 15;
#pragma unroll
    for (int r = 0; r < 4; r++) {
        int node = n0 + tile * 16 + kg * 4 + r;
        if (node >= nN) continue;
        float ri = rs_in[node];
        float ro = RELU_OUTSCALE ? rs_out[node] : 1.0f;
#pragma unroll
        for (int c = 0; c < 4; c++) {
            int col = half * 64 + c * 16 + ocol;
            float v = acc[c][r] * ri + bias[col];
            if (RELU_OUTSCALE) v = fmaxf(v, 0.0f) * ro;
            if (OUT_BF16) {
                ((bf16_t*)outp)[(size_t)node * D + col] = f2bf(v);
            } else {
                ((float*)outp)[(size_t)node * D + col] = v;
            }
        }
    }
}
#undef LDW

static inline size_t align16(size_t x) { return (x + 15) & ~(size_t)15; }

extern "C" void kernel_launch(void* const* d_in, const int* in_sizes, int n_in,
                              void* d_out, int out_size, void* d_ws, size_t ws_size,
                              hipStream_t stream) {
    const float* x   = (const float*)d_in[0];
    const int*   src = (const int*)d_in[1];
    const int*   dst = (const int*)d_in[2];
    const float* W1  = (const float*)d_in[3];
    const float* b1  = (const float*)d_in[4];
    const float* W2  = (const float*)d_in[5];
    const float* b2  = (const float*)d_in[6];
    float* out = (float*)d_out;

    char* p = (char*)d_ws;
    int*            cnt_s   = (int*)p;            p += align16(N_NODES * sizeof(int));
    int*            cnt_d   = (int*)p;            p += align16(N_NODES * sizeof(int));
    int*            ovf_cnt = (int*)p;            p += align16(16 * sizeof(int));
    int2*           ovf     = (int2*)p;           p += align16((size_t)OVF_CAP * sizeof(int2));
    unsigned short* bucket  = (unsigned short*)p; p += align16((size_t)NPAD * CAP * sizeof(unsigned short));
    float*          rs_out  = (float*)p;          p += align16(N_NODES * sizeof(float));
    float*          rs_in   = (float*)p;          p += align16(N_NODES * sizeof(float));
    bf16_t*         Wf1     = (bf16_t*)p;         p += align16((size_t)2 * 2048 * 8 * sizeof(bf16_t));
    bf16_t*         Wf2     = (bf16_t*)p;         p += align16((size_t)2 * 2048 * 8 * sizeof(bf16_t));
    unsigned int*   H       = (unsigned int*)p;   p += align16((size_t)NCH * NPART * sizeof(unsigned int));
    unsigned int*   OFF     = (unsigned int*)p;   p += align16((size_t)NCH * NPART * sizeof(unsigned int));
    unsigned int*   binTot  = (unsigned int*)p;   p += align16(NPART * sizeof(unsigned int));
    unsigned int*   binned  = (unsigned int*)p;   p += align16((size_t)N_EDGES * sizeof(unsigned int));
    bf16_t*         xs      = (bf16_t*)p;         p += align16((size_t)N_NODES * D * sizeof(bf16_t));
    bf16_t*         hs      = (bf16_t*)p;         // 12.8 MB
    // SH (NCH*NW u32 = 6.4 MB) aliases hs: written in phase A, read in phase C,
    // both strictly before fused layer 1 writes hs.
    unsigned int*   SH      = (unsigned int*)hs;

    // single cooperative preprocessing kernel (wsplit + hist + scan + place +
    // cnt_s + scatter + cnt_d + prescale), 256 blocks = 1/CU, 3 grid syncs.
    ushort4* xs4 = (ushort4*)xs;
    void* args[] = {&x, &src, &dst, &W1, &W2, &Wf1, &Wf2, &H, &OFF, &binTot,
                    &binned, &SH, &cnt_s, &cnt_d, &bucket, &ovf_cnt, &ovf,
                    &rs_out, &rs_in, &xs4};
    hipLaunchCooperativeKernel((void*)preproc_kernel, dim3(NPART), dim3(1024),
                               args, 0, stream);

    int fgrid = (N_NODES + 63) / 64;   // 64 nodes per fused block

    // layer 1: hs = bf16( relu(rs_in * (gather(xs) @ W1) + b1) * rs_out )
    fused_layer_kernel<true, true><<<fgrid, 512, 0, stream>>>(
        (const uint4*)xs, cnt_d, bucket, ovf_cnt, ovf, rs_in, rs_out, Wf1, b1, hs, N_NODES);

    // layer 2: out = rs_in * (gather(hs) @ W2) + b2   (fp32 row-major)
    fused_layer_kernel<false, false><<<fgrid, 512, 0, stream>>>(
        (const uint4*)hs, cnt_d, bucket, ovf_cnt, ovf, rs_in, rs_out, Wf2, b2, out, N_NODES);
}

// Round 14
// 219.010 us; speedup vs baseline: 1.4112x; 1.4112x over previous
//
#include <hip/hip_runtime.h>

#define N_NODES 50000
#define N_EDGES 800000
#define D 128
#define CAP 48      // bucket capacity per dst node (max in-degree ~45 for this dataset)
#define OVF_CAP 4096

#define BINS 40     // dst partitions (one scatter2 block each)
#define PNODES 1250 // nodes per partition = 50000/40
#define B1 64       // binning blocks (hist40/place40 share chunking)
#define CH1 ((N_EDGES + B1 - 1) / B1)   // 12500 edges per chunk
#define NW (N_NODES / 4)                // packed byte-counter words = 12500
#define WPB ((NW + B1 - 1) / B1)        // sreduce words per place40 block = 196

typedef unsigned short bf16_t;
typedef __attribute__((ext_vector_type(8))) short short8v;   // 8 bf16 = 4 VGPR (MFMA A/B frag)
typedef __attribute__((ext_vector_type(4))) float f32x4;     // MFMA C/D frag

__device__ inline float bf2f(bf16_t u) {
    union { unsigned int i; float f; } v;
    v.i = ((unsigned int)u) << 16;
    return v.f;
}
__device__ inline bf16_t f2bf(float f) {
    union { float f; unsigned int i; } v;
    v.f = f;
    unsigned int u = v.i;
    unsigned int r = (u + 0x7FFFu + ((u >> 16) & 1u)) >> 16;  // RNE
    return (bf16_t)r;
}
// bf16 pair packed in a u32 (little-endian: lo half = even col, hi half = odd col)
__device__ inline float u2f_lo(unsigned int u) {
    union { unsigned int i; float f; } x; x.i = u << 16; return x.f;
}
__device__ inline float u2f_hi(unsigned int u) {
    union { unsigned int i; float f; } x; x.i = u & 0xFFFF0000u; return x.f;
}

// =============== two-phase binned scatter (r9 structure; scan40+wsplit folded) ===============
// r13 lesson: grid.sync() costs more than launch gaps on 8 non-coherent XCDs.
// Cheap alternative: consumers recompute the tiny 64x40 scan locally (~10 KB,
// ~us) instead of a separate 1-block scan40 dispatch; wsplit rides in hist40
// block 0. 8 dispatches -> 6, zero barriers added.

// hist40: per-chunk 40-bin dst hist + src SWAR hist; block 0 also does wsplit
// and zeroes ovf_cnt.
__global__ __launch_bounds__(1024) void hist40_kernel(const int* __restrict__ src,
                                                      const int* __restrict__ dst,
                                                      unsigned int* __restrict__ H40,
                                                      unsigned int* __restrict__ SH,
                                                      int* __restrict__ ovf_cnt,
                                                      const float* __restrict__ W1,
                                                      const float* __restrict__ W2,
                                                      bf16_t* __restrict__ Wf1,
                                                      bf16_t* __restrict__ Wf2, int nE) {
    __shared__ unsigned int hb[BINS];
    __shared__ unsigned int hs[NW];   // 50 KB src byte counters
    if (blockIdx.x == 0) {
        if (threadIdx.x == 0) ovf_cnt[0] = 0;
        // folded wsplit: 4096 work items (2048 frags x 2 layers), 4 per thread
        for (int fg = (int)threadIdx.x; fg < 4096; fg += 1024) {
            const float* W = (fg >= 2048) ? W2 : W1;
            bf16_t* Wf = (fg >= 2048) ? Wf2 : Wf1;
            int flat = fg & 2047;
            int lane = flat & 63;
            int c = (flat >> 6) & 7;
            int ks = flat >> 9;
            int n = c * 16 + (lane & 15);
            int kb = ks * 32 + (lane >> 4) * 8;
#pragma unroll
            for (int j = 0; j < 8; j++) {
                float w = W[(size_t)(kb + j) * D + n];
                bf16_t hi = f2bf(w);
                bf16_t lo = f2bf(w - bf2f(hi));
                Wf[(size_t)flat * 8 + j] = hi;
                Wf[(size_t)(2048 + flat) * 8 + j] = lo;
            }
        }
    }
    for (int i = threadIdx.x; i < NW; i += 1024) hs[i] = 0u;
    if (threadIdx.x < BINS) hb[threadIdx.x] = 0u;
    __syncthreads();
    int e0 = blockIdx.x * CH1;
    int e1 = min(e0 + CH1, nE);
    for (int e = e0 + (int)threadIdx.x; e < e1; e += 1024) {
        int s = src[e];
        int d = dst[e];
        atomicAdd(&hs[s >> 2], 1u << (8 * (s & 3)));   // per-chunk count <= out-degree < 256
        atomicAdd(&hb[d / PNODES], 1u);
    }
    __syncthreads();
    if (threadIdx.x < BINS) H40[blockIdx.x * BINS + threadIdx.x] = hb[threadIdx.x];
    unsigned int* SHb = SH + (size_t)blockIdx.x * NW;
    for (int i = threadIdx.x; i < NW; i += 1024) SHb[i] = hs[i];
}

// place40: derives its own (chunk,bin) offsets from H40 (scan40 folded in),
// bins edges, and appends the cnt_s reduce.
__global__ __launch_bounds__(1024) void place40_kernel(const int* __restrict__ src,
                                                       const int* __restrict__ dst,
                                                       const unsigned int* __restrict__ H40,
                                                       unsigned int* __restrict__ binned,
                                                       const unsigned int* __restrict__ SH,
                                                       int* __restrict__ cnt_s, int nE) {
    __shared__ unsigned int cur[BINS];
    __shared__ unsigned int sTot[BINS];
    __shared__ unsigned int sPre[BINS];
    int t = (int)threadIdx.x;
    if (t < BINS) {
        unsigned int pre = 0, tot = 0;
        int myb = (int)blockIdx.x;
        for (int b2 = 0; b2 < B1; b2++) {
            unsigned int v = H40[b2 * BINS + t];
            if (b2 < myb) pre += v;
            tot += v;
        }
        sTot[t] = tot;
        sPre[t] = pre;
    }
    __syncthreads();
    if (t == 0) {
        unsigned int r = 0;
        for (int q = 0; q < BINS; q++) { unsigned int v = sTot[q]; sTot[q] = r; r += v; }
    }
    __syncthreads();
    if (t < BINS) cur[t] = sPre[t] + sTot[t];   // global exclusive offset for this chunk+bin
    __syncthreads();
    int e0 = blockIdx.x * CH1;
    int e1 = min(e0 + CH1, nE);
    for (int e = e0 + t; e < e1; e += 1024) {
        int s = src[e];
        int d = dst[e];
        int bin = d / PNODES;
        unsigned int pos = atomicAdd(&cur[bin], 1u);
        binned[pos] = (unsigned int)(d - bin * PNODES) | ((unsigned int)s << 16);
    }
    // appended sreduce: cnt_s from the (complete, hist40-written) SH array
    int w = blockIdx.x * WPB + t;
    if (t < WPB && w < NW) {
        unsigned int run = 0;
#pragma unroll 8
        for (int b = 0; b < B1; b++) run += SH[(size_t)b * NW + w];  // SWAR
        int4 c;
        c.x = (int)(run & 0xFFu); c.y = (int)((run >> 8) & 0xFFu);
        c.z = (int)((run >> 16) & 0xFFu); c.w = (int)(run >> 24);
        ((int4*)cnt_s)[w] = c;
    }
}

// scatter2: derives bin base/total from H40 (scan40 folded in), builds the
// 1250-node bucket region in LDS from its contiguous bin segment, dense writeout.
__global__ __launch_bounds__(1024) void scatter2_kernel(
    const unsigned int* __restrict__ binned, const unsigned int* __restrict__ H40,
    unsigned short* __restrict__ bucket, int* __restrict__ cnt_d,
    int* __restrict__ ovf_cnt, int2* __restrict__ ovf) {
    __shared__ unsigned short bk[PNODES * CAP];  // 120 KB
    __shared__ unsigned int cur[PNODES];         // 5 KB
    __shared__ unsigned int sTot[BINS];
    __shared__ unsigned int sBase[BINS];
    const int j = blockIdx.x;
    const int nbeg = j * PNODES;
    int t = (int)threadIdx.x;
    if (t < BINS) {
        unsigned int tot = 0;
        for (int b2 = 0; b2 < B1; b2++) tot += H40[b2 * BINS + t];
        sTot[t] = tot;
    }
    __syncthreads();
    if (t == 0) {
        unsigned int r = 0;
        for (int q = 0; q < BINS; q++) { sBase[q] = r; r += sTot[q]; }
    }
    for (int i = t; i < PNODES; i += 1024) cur[i] = 0u;
    __syncthreads();
    unsigned int b0 = sBase[j];
    unsigned int n = sTot[j];
    for (unsigned int i = t; i < n; i += 1024) {
        unsigned int v = binned[b0 + i];
        unsigned int dl = v & 0xFFFFu;
        unsigned int s = v >> 16;
        unsigned int q = atomicAdd(&cur[dl], 1u);
        if (q < CAP) {
            bk[dl * CAP + q] = (unsigned short)s;
        } else {
            int o = atomicAdd(ovf_cnt, 1);
            if (o < OVF_CAP) ovf[o] = make_int2(nbeg + (int)dl, (int)s);
        }
    }
    __syncthreads();
    uint4* gb = (uint4*)(bucket + (size_t)nbeg * CAP);
    const uint4* lb = (const uint4*)bk;
    const int n16 = PNODES * CAP * 2 / 16;   // 7500 uint4
    for (int i = t; i < n16; i += 1024) gb[i] = lb[i];
    for (int i = t; i < PNODES; i += 1024) cnt_d[nbeg + i] = (int)cur[i];
}

// ---------------- fused: rs arrays + xs = bf16(x * rs_out), ROW-MAJOR ----------------
__global__ void prescale_kernel(const float4* __restrict__ x, const int* __restrict__ cnt_s,
                                const int* __restrict__ cnt_d,
                                float* __restrict__ rs_out, float* __restrict__ rs_in,
                                ushort4* __restrict__ xs4, int nN) {
    int node = blockIdx.x * 8 + (threadIdx.x >> 5);
    int c = threadIdx.x & 31;
    if (node >= nN) return;
    float rs_o = 0.0f;
    if (c == 0) {
        rs_o = rsqrtf(fmaxf((float)cnt_s[node], 1.0f));
        rs_out[node] = rs_o;
        rs_in[node] = rsqrtf(fmaxf((float)cnt_d[node], 1.0f));
    }
    rs_o = __shfl(rs_o, threadIdx.x & 32);  // broadcast from node's lane 0 / 32
    float4 v = x[(size_t)node * 32 + c];
    ushort4 o;
    o.x = f2bf(v.x * rs_o);
    o.y = f2bf(v.y * rs_o);
    o.z = f2bf(v.z * rs_o);
    o.w = f2bf(v.w * rs_o);
    xs4[(size_t)node * 32 + c] = o;   // row-major: node row = 256 B
}

// =============== fused gather + ovf-patch + MFMA gemm, 512 threads (EXACT r9 body) ===============
#define LDW 132
template <bool RELU_OUTSCALE, bool OUT_BF16>
__global__ __launch_bounds__(512) void fused_layer_kernel(
    const uint4* __restrict__ xsrc,          // bf16 row-major src features: 16 uint4/row
    const int* __restrict__ cnt_d,
    const unsigned short* __restrict__ bucket,
    const int* __restrict__ ovf_cnt, const int2* __restrict__ ovf,
    const float* __restrict__ rs_in, const float* __restrict__ rs_out,
    const bf16_t* __restrict__ Wf, const float* __restrict__ bias,
    void* __restrict__ outp, int nN) {
    __shared__ float sA[64 * LDW];   // 33.8 KB
    int tid = (int)threadIdx.x;
    int n0 = blockIdx.x * 64;
    int lane16 = tid & 15;
    int grp = tid >> 4;        // 0..31

    // ---- phase 1: gather 64 node rows into sA (2 rows/thread) ----
#define ACC8(v)                                              \
    a[0] += u2f_lo(v.x); a[1] += u2f_hi(v.x);                \
    a[2] += u2f_lo(v.y); a[3] += u2f_hi(v.y);                \
    a[4] += u2f_lo(v.z); a[5] += u2f_hi(v.z);                \
    a[6] += u2f_lo(v.w); a[7] += u2f_hi(v.w);
#pragma unroll
    for (int r = 0; r < 2; r++) {
        int ln = r * 32 + grp;     // local node 0..63
        int node = n0 + ln;
        float a[8];
#pragma unroll
        for (int k = 0; k < 8; k++) a[k] = 0.f;
        if (node < nN) {
            const unsigned short* bk = bucket + (size_t)node * CAP;
            int cnt = min(cnt_d[node], CAP);
            int e = 0;
            for (; e + 3 < cnt; e += 4) {
                int s0 = bk[e], s1 = bk[e + 1], s2 = bk[e + 2], s3 = bk[e + 3];
                uint4 v0 = xsrc[(size_t)s0 * 16 + lane16];
                uint4 v1 = xsrc[(size_t)s1 * 16 + lane16];
                uint4 v2 = xsrc[(size_t)s2 * 16 + lane16];
                uint4 v3 = xsrc[(size_t)s3 * 16 + lane16];
                ACC8(v0) ACC8(v1) ACC8(v2) ACC8(v3)
            }
            for (; e < cnt; e++) {
                int s0 = bk[e];
                uint4 v0 = xsrc[(size_t)s0 * 16 + lane16];
                ACC8(v0)
            }
        }
        float* row = sA + ln * LDW + lane16 * 8;
#pragma unroll
        for (int k = 0; k < 8; k++) row[k] = a[k];
    }
#undef ACC8

    // ---- overflow patch (uniform branch; no-op when list empty) ----
    int novf = min(*ovf_cnt, OVF_CAP);
    if (novf > 0) {
        __syncthreads();
        for (int i = tid; i < novf; i += 512) {
            int2 ds = ovf[i];
            int ln = ds.x - n0;
            if ((unsigned)ln < 64u) {
                const uint4* xr = xsrc + (size_t)ds.y * 16;
                for (int c = 0; c < 16; c++) {
                    uint4 v = xr[c];
                    float* q = sA + ln * LDW + c * 8;
                    atomicAdd(q + 0, u2f_lo(v.x)); atomicAdd(q + 1, u2f_hi(v.x));
                    atomicAdd(q + 2, u2f_lo(v.y)); atomicAdd(q + 3, u2f_hi(v.y));
                    atomicAdd(q + 4, u2f_lo(v.z)); atomicAdd(q + 5, u2f_hi(v.z));
                    atomicAdd(q + 6, u2f_lo(v.w)); atomicAdd(q + 7, u2f_hi(v.w));
                }
            }
        }
    }
    __syncthreads();

    // ---- phase 2: split-bf16 MFMA from LDS; wave pair per 16-node tile ----
    int lane = tid & 63;
    int wave = tid >> 6;       // 0..7
    int tile = wave >> 1;      // 0..3: node tile
    int half = wave & 1;       // 0..1: column half (64 cols)
    int ar = lane & 15;        // A row within tile
    int kg = lane >> 4;        // k-subchunk of 8
    const float* ap = sA + (tile * 16 + ar) * LDW + kg * 8;
    short8v ahi[4], alo[4];
#pragma unroll
    for (int ks = 0; ks < 4; ks++) {
#pragma unroll
        for (int j = 0; j < 8; j++) {
            float av = ap[ks * 32 + j];
            bf16_t h = f2bf(av);
            ahi[ks][j] = (short)h;
            alo[ks][j] = (short)f2bf(av - bf2f(h));
        }
    }

    f32x4 acc[4];
#pragma unroll
    for (int c = 0; c < 4; c++) acc[c] = (f32x4){0.f, 0.f, 0.f, 0.f};

    const short8v* Bh = (const short8v*)Wf;        // 2048 hi frags
    const short8v* Bl = Bh + 2048;                 // 2048 lo frags
#pragma unroll
    for (int ks = 0; ks < 4; ks++) {
#pragma unroll
        for (int c = 0; c < 4; c++) {
            int off = (ks * 8 + half * 4 + c) * 64 + lane;
            short8v wh = Bh[off];
            short8v wl = Bl[off];
            acc[c] = __builtin_amdgcn_mfma_f32_16x16x32_bf16(ahi[ks], wh, acc[c], 0, 0, 0);
            acc[c] = __builtin_amdgcn_mfma_f32_16x16x32_bf16(alo[ks], wh, acc[c], 0, 0, 0);
            acc[c] = __builtin_amdgcn_mfma_f32_16x16x32_bf16(ahi[ks], wl, acc[c], 0, 0, 0);
        }
    }

    // ---- epilogue: col = half*64 + c*16 + (lane&15), node = n0 + tile*16 + kg*4 + r ----
    int ocol = lane & 15;
#pragma unroll
    for (int r = 0; r < 4; r++) {
        int node = n0 + tile * 16 + kg * 4 + r;
        if (node >= nN) continue;
        float ri = rs_in[node];
        float ro = RELU_OUTSCALE ? rs_out[node] : 1.0f;
#pragma unroll
        for (int c = 0; c < 4; c++) {
            int col = half * 64 + c * 16 + ocol;
            float v = acc[c][r] * ri + bias[col];
            if (RELU_OUTSCALE) v = fmaxf(v, 0.0f) * ro;
            if (OUT_BF16) {
                ((bf16_t*)outp)[(size_t)node * D + col] = f2bf(v);
            } else {
                ((float*)outp)[(size_t)node * D + col] = v;
            }
        }
    }
}
#undef LDW

static inline size_t align16(size_t x) { return (x + 15) & ~(size_t)15; }

extern "C" void kernel_launch(void* const* d_in, const int* in_sizes, int n_in,
                              void* d_out, int out_size, void* d_ws, size_t ws_size,
                              hipStream_t stream) {
    const float* x   = (const float*)d_in[0];
    const int*   src = (const int*)d_in[1];
    const int*   dst = (const int*)d_in[2];
    const float* W1  = (const float*)d_in[3];
    const float* b1  = (const float*)d_in[4];
    const float* W2  = (const float*)d_in[5];
    const float* b2  = (const float*)d_in[6];
    float* out = (float*)d_out;

    char* p = (char*)d_ws;
    int*            cnt_s   = (int*)p;            p += align16(N_NODES * sizeof(int));
    int*            cnt_d   = (int*)p;            p += align16(N_NODES * sizeof(int));
    int*            ovf_cnt = (int*)p;            p += align16(16 * sizeof(int));
    int2*           ovf     = (int2*)p;           p += align16((size_t)OVF_CAP * sizeof(int2));
    unsigned short* bucket  = (unsigned short*)p; p += align16((size_t)N_NODES * CAP * sizeof(unsigned short));
    float*          rs_out  = (float*)p;          p += align16(N_NODES * sizeof(float));
    float*          rs_in   = (float*)p;          p += align16(N_NODES * sizeof(float));
    bf16_t*         Wf1     = (bf16_t*)p;         p += align16((size_t)2 * 2048 * 8 * sizeof(bf16_t));
    bf16_t*         Wf2     = (bf16_t*)p;         p += align16((size_t)2 * 2048 * 8 * sizeof(bf16_t));
    unsigned int*   H40     = (unsigned int*)p;   p += align16((size_t)B1 * BINS * sizeof(unsigned int));
    unsigned int*   binned  = (unsigned int*)p;   p += align16((size_t)N_EDGES * sizeof(unsigned int));
    unsigned int*   SH      = (unsigned int*)p;   p += align16((size_t)B1 * NW * sizeof(unsigned int));
    bf16_t*         xs      = (bf16_t*)p;         p += align16((size_t)N_NODES * D * sizeof(bf16_t));
    bf16_t*         hs      = (bf16_t*)p;         // separate 12.8 MB buffer

    // binned scatter, 4 dispatches (wsplit folded into hist40; scan40 folded
    // into place40/scatter2 via local recomputation)
    hist40_kernel<<<B1, 1024, 0, stream>>>(src, dst, H40, SH, ovf_cnt,
                                           W1, W2, Wf1, Wf2, N_EDGES);
    place40_kernel<<<B1, 1024, 0, stream>>>(src, dst, H40, binned, SH, cnt_s, N_EDGES);
    scatter2_kernel<<<BINS, 1024, 0, stream>>>(binned, H40, bucket, cnt_d, ovf_cnt, ovf);

    // rs arrays + xs = bf16(x * rs_out), row-major
    prescale_kernel<<<(N_NODES + 7) / 8, 256, 0, stream>>>((const float4*)x, cnt_s, cnt_d,
                                                           rs_out, rs_in, (ushort4*)xs, N_NODES);

    int fgrid = (N_NODES + 63) / 64;   // 64 nodes per fused block

    // layer 1: hs = bf16( relu(rs_in * (gather(xs) @ W1) + b1) * rs_out )
    fused_layer_kernel<true, true><<<fgrid, 512, 0, stream>>>(
        (const uint4*)xs, cnt_d, bucket, ovf_cnt, ovf, rs_in, rs_out, Wf1, b1, hs, N_NODES);

    // layer 2: out = rs_in * (gather(hs) @ W2) + b2   (fp32 row-major)
    fused_layer_kernel<false, false><<<fgrid, 512, 0, stream>>>(
        (const uint4*)hs, cnt_d, bucket, ovf_cnt, ovf, rs_in, rs_out, Wf2, b2, out, N_NODES);
}

// Round 15
// 196.872 us; speedup vs baseline: 1.5699x; 1.1125x over previous
//
#include <hip/hip_runtime.h>

#define N_NODES 50000
#define N_EDGES 800000
#define D 128
#define CAP 48      // bucket capacity per dst node (max in-degree ~45 for this dataset)
#define OVF_CAP 4096

#define BINS 40     // dst partitions (one scatter2 block each)
#define PNODES 1250 // nodes per partition = 50000/40
#define B1 64       // binning blocks (hist40/place40 share chunking)
#define CH1 ((N_EDGES + B1 - 1) / B1)   // 12500 edges per chunk
#define NW (N_NODES / 4)                // packed byte-counter words = 12500
#define WPB ((NW + B1 - 1) / B1)        // sreduce words per place40 block = 196

typedef unsigned short bf16_t;
typedef __attribute__((ext_vector_type(8))) short short8v;   // 8 bf16 = 4 VGPR (MFMA A/B frag)
typedef __attribute__((ext_vector_type(4))) float f32x4;     // MFMA C/D frag

__device__ inline float bf2f(bf16_t u) {
    union { unsigned int i; float f; } v;
    v.i = ((unsigned int)u) << 16;
    return v.f;
}
__device__ inline bf16_t f2bf(float f) {
    union { float f; unsigned int i; } v;
    v.f = f;
    unsigned int u = v.i;
    unsigned int r = (u + 0x7FFFu + ((u >> 16) & 1u)) >> 16;  // RNE
    return (bf16_t)r;
}
// bf16 pair packed in a u32 (little-endian: lo half = even col, hi half = odd col)
__device__ inline float u2f_lo(unsigned int u) {
    union { unsigned int i; float f; } x; x.i = u << 16; return x.f;
}
__device__ inline float u2f_hi(unsigned int u) {
    union { unsigned int i; float f; } x; x.i = u & 0xFFFF0000u; return x.f;
}

// =============== two-phase binned scatter (r9 exact — best measured 197.3) ===============
// hist40 also zeroes ovf_cnt (replaces the hipMemsetAsync dispatch);
// place40 also reduces SH -> cnt_s (replaces the sreduce dispatch).
__global__ __launch_bounds__(1024) void hist40_kernel(const int* __restrict__ src,
                                                      const int* __restrict__ dst,
                                                      unsigned int* __restrict__ H40,
                                                      unsigned int* __restrict__ SH,
                                                      int* __restrict__ ovf_cnt, int nE) {
    __shared__ unsigned int hb[BINS];
    __shared__ unsigned int hs[NW];   // 50 KB src byte counters
    if (blockIdx.x == 0 && threadIdx.x == 0) ovf_cnt[0] = 0;
    for (int i = threadIdx.x; i < NW; i += 1024) hs[i] = 0u;
    if (threadIdx.x < BINS) hb[threadIdx.x] = 0u;
    __syncthreads();
    int e0 = blockIdx.x * CH1;
    int e1 = min(e0 + CH1, nE);
    for (int e = e0 + (int)threadIdx.x; e < e1; e += 1024) {
        int s = src[e];
        int d = dst[e];
        atomicAdd(&hs[s >> 2], 1u << (8 * (s & 3)));   // per-chunk count <= out-degree < 256
        atomicAdd(&hb[d / PNODES], 1u);
    }
    __syncthreads();
    if (threadIdx.x < BINS) H40[blockIdx.x * BINS + threadIdx.x] = hb[threadIdx.x];
    unsigned int* SHb = SH + (size_t)blockIdx.x * NW;
    for (int i = threadIdx.x; i < NW; i += 1024) SHb[i] = hs[i];
}

__global__ void scan40_kernel(const unsigned int* __restrict__ H40,
                              unsigned int* __restrict__ OFF40,
                              unsigned int* __restrict__ binBase,
                              unsigned int* __restrict__ binTot) {
    __shared__ unsigned int part[B1 * BINS];   // 10 KB
    __shared__ unsigned int tot[BINS], base[BINS];
    int j = (int)threadIdx.x;
    if (j < BINS) {
        unsigned int run = 0;
        for (int b = 0; b < B1; b++) {
            part[b * BINS + j] = run;
            run += H40[b * BINS + j];
        }
        tot[j] = run;
    }
    __syncthreads();
    if (j == 0) {
        unsigned int run = 0;
        for (int q = 0; q < BINS; q++) { base[q] = run; run += tot[q]; }
    }
    __syncthreads();
    if (j < BINS) {
        binBase[j] = base[j];
        binTot[j] = tot[j];
        for (int b = 0; b < B1; b++) OFF40[b * BINS + j] = part[b * BINS + j] + base[j];
    }
}

__global__ __launch_bounds__(1024) void place40_kernel(const int* __restrict__ src,
                                                       const int* __restrict__ dst,
                                                       const unsigned int* __restrict__ OFF40,
                                                       unsigned int* __restrict__ binned,
                                                       const unsigned int* __restrict__ SH,
                                                       int* __restrict__ cnt_s, int nE) {
    __shared__ unsigned int cur[BINS];
    if (threadIdx.x < BINS) cur[threadIdx.x] = OFF40[blockIdx.x * BINS + threadIdx.x];
    __syncthreads();
    int e0 = blockIdx.x * CH1;
    int e1 = min(e0 + CH1, nE);
    for (int e = e0 + (int)threadIdx.x; e < e1; e += 1024) {
        int s = src[e];
        int d = dst[e];
        int bin = d / PNODES;
        unsigned int pos = atomicAdd(&cur[bin], 1u);
        binned[pos] = (unsigned int)(d - bin * PNODES) | ((unsigned int)s << 16);
    }
    // appended sreduce: cnt_s from the (complete, hist40-written) SH array
    int w = blockIdx.x * WPB + (int)threadIdx.x;
    if ((int)threadIdx.x < WPB && w < NW) {
        unsigned int run = 0;
#pragma unroll 8
        for (int b = 0; b < B1; b++) run += SH[(size_t)b * NW + w];  // SWAR
        int4 c;
        c.x = (int)(run & 0xFFu); c.y = (int)((run >> 8) & 0xFFu);
        c.z = (int)((run >> 16) & 0xFFu); c.w = (int)(run >> 24);
        ((int4*)cnt_s)[w] = c;
    }
}

__global__ __launch_bounds__(1024) void scatter2_kernel(
    const unsigned int* __restrict__ binned, const unsigned int* __restrict__ binBase,
    const unsigned int* __restrict__ binTot, unsigned short* __restrict__ bucket,
    int* __restrict__ cnt_d, int* __restrict__ ovf_cnt, int2* __restrict__ ovf) {
    __shared__ unsigned short bk[PNODES * CAP];  // 120 KB
    __shared__ unsigned int cur[PNODES];         // 5 KB
    const int j = blockIdx.x;
    const int nbeg = j * PNODES;
    for (int i = threadIdx.x; i < PNODES; i += 1024) cur[i] = 0u;
    __syncthreads();
    unsigned int b0 = binBase[j];
    unsigned int n = binTot[j];
    for (unsigned int i = threadIdx.x; i < n; i += 1024) {
        unsigned int v = binned[b0 + i];
        unsigned int dl = v & 0xFFFFu;
        unsigned int s = v >> 16;
        unsigned int q = atomicAdd(&cur[dl], 1u);
        if (q < CAP) {
            bk[dl * CAP + q] = (unsigned short)s;
        } else {
            int o = atomicAdd(ovf_cnt, 1);
            if (o < OVF_CAP) ovf[o] = make_int2(nbeg + (int)dl, (int)s);
        }
    }
    __syncthreads();
    uint4* gb = (uint4*)(bucket + (size_t)nbeg * CAP);
    const uint4* lb = (const uint4*)bk;
    const int n16 = PNODES * CAP * 2 / 16;   // 7500 uint4
    for (int i = threadIdx.x; i < n16; i += 1024) gb[i] = lb[i];
    for (int i = threadIdx.x; i < PNODES; i += 1024) cnt_d[nbeg + i] = (int)cur[i];
}

// ---------------- fused: rs arrays + xs = bf16(x * rs_out), ROW-MAJOR ----------------
__global__ void prescale_kernel(const float4* __restrict__ x, const int* __restrict__ cnt_s,
                                const int* __restrict__ cnt_d,
                                float* __restrict__ rs_out, float* __restrict__ rs_in,
                                ushort4* __restrict__ xs4, int nN) {
    int node = blockIdx.x * 8 + (threadIdx.x >> 5);
    int c = threadIdx.x & 31;
    if (node >= nN) return;
    float rs_o = 0.0f;
    if (c == 0) {
        rs_o = rsqrtf(fmaxf((float)cnt_s[node], 1.0f));
        rs_out[node] = rs_o;
        rs_in[node] = rsqrtf(fmaxf((float)cnt_d[node], 1.0f));
    }
    rs_o = __shfl(rs_o, threadIdx.x & 32);  // broadcast from node's lane 0 / 32
    float4 v = x[(size_t)node * 32 + c];
    ushort4 o;
    o.x = f2bf(v.x * rs_o);
    o.y = f2bf(v.y * rs_o);
    o.z = f2bf(v.z * rs_o);
    o.w = f2bf(v.w * rs_o);
    xs4[(size_t)node * 32 + c] = o;   // row-major: node row = 256 B
}

// ---------------- W hi/lo split into MFMA B-fragment layout ----------------
__global__ void wsplit_kernel(const float* __restrict__ W1, bf16_t* __restrict__ Wf1,
                              const float* __restrict__ W2, bf16_t* __restrict__ Wf2) {
    const float* W = blockIdx.y ? W2 : W1;
    bf16_t* Wf = blockIdx.y ? Wf2 : Wf1;
    int flat = blockIdx.x * 256 + (int)threadIdx.x;   // 0..2047 (grid.x = 8)
    int lane = flat & 63;
    int c = (flat >> 6) & 7;
    int ks = flat >> 9;
    int n = c * 16 + (lane & 15);
    int kb = ks * 32 + (lane >> 4) * 8;
#pragma unroll
    for (int j = 0; j < 8; j++) {
        float w = W[(size_t)(kb + j) * D + n];
        bf16_t hi = f2bf(w);
        bf16_t lo = f2bf(w - bf2f(hi));
        Wf[(size_t)flat * 8 + j] = hi;
        Wf[(size_t)(2048 + flat) * 8 + j] = lo;
    }
}

// =============== fused gather + ovf-patch + MFMA gemm, 512 threads ===============
// r8 evidence: 43.7 us, Occupancy 24.7% (grid-limited: 782 blocks x 4 waves =
// 12 waves/CU cap), VALUBusy 21%, fabric 2 TB/s -> latency-bound gather.
// Fix: 8 waves/block (same 64-node tile, same LDS): phase 1 gathers 2 rows per
// thread (2x in-flight loads per CU); phase 2 splits each 16-node tile across
// a wave PAIR (each wave computes a 64-col half, acc[4]).
#define LDW 132
template <bool RELU_OUTSCALE, bool OUT_BF16>
__global__ __launch_bounds__(512) void fused_layer_kernel(
    const uint4* __restrict__ xsrc,          // bf16 row-major src features: 16 uint4/row
    const int* __restrict__ cnt_d,
    const unsigned short* __restrict__ bucket,
    const int* __restrict__ ovf_cnt, const int2* __restrict__ ovf,
    const float* __restrict__ rs_in, const float* __restrict__ rs_out,
    const bf16_t* __restrict__ Wf, const float* __restrict__ bias,
    void* __restrict__ outp, int nN) {
    __shared__ float sA[64 * LDW];   // 33.8 KB
    int tid = (int)threadIdx.x;
    int n0 = blockIdx.x * 64;
    int lane16 = tid & 15;
    int grp = tid >> 4;        // 0..31

    // ---- phase 1: gather 64 node rows into sA (2 rows/thread) ----
#define ACC8(v)                                              \
    a[0] += u2f_lo(v.x); a[1] += u2f_hi(v.x);                \
    a[2] += u2f_lo(v.y); a[3] += u2f_hi(v.y);                \
    a[4] += u2f_lo(v.z); a[5] += u2f_hi(v.z);                \
    a[6] += u2f_lo(v.w); a[7] += u2f_hi(v.w);
#pragma unroll
    for (int r = 0; r < 2; r++) {
        int ln = r * 32 + grp;     // local node 0..63
        int node = n0 + ln;
        float a[8];
#pragma unroll
        for (int k = 0; k < 8; k++) a[k] = 0.f;
        if (node < nN) {
            const unsigned short* bk = bucket + (size_t)node * CAP;
            int cnt = min(cnt_d[node], CAP);
            int e = 0;
            for (; e + 3 < cnt; e += 4) {
                int s0 = bk[e], s1 = bk[e + 1], s2 = bk[e + 2], s3 = bk[e + 3];
                uint4 v0 = xsrc[(size_t)s0 * 16 + lane16];
                uint4 v1 = xsrc[(size_t)s1 * 16 + lane16];
                uint4 v2 = xsrc[(size_t)s2 * 16 + lane16];
                uint4 v3 = xsrc[(size_t)s3 * 16 + lane16];
                ACC8(v0) ACC8(v1) ACC8(v2) ACC8(v3)
            }
            for (; e < cnt; e++) {
                int s0 = bk[e];
                uint4 v0 = xsrc[(size_t)s0 * 16 + lane16];
                ACC8(v0)
            }
        }
        float* row = sA + ln * LDW + lane16 * 8;
#pragma unroll
        for (int k = 0; k < 8; k++) row[k] = a[k];
    }
#undef ACC8

    // ---- overflow patch (uniform branch; no-op when list empty) ----
    int novf = min(*ovf_cnt, OVF_CAP);
    if (novf > 0) {
        __syncthreads();
        for (int i = tid; i < novf; i += 512) {
            int2 ds = ovf[i];
            int ln = ds.x - n0;
            if ((unsigned)ln < 64u) {
                const uint4* xr = xsrc + (size_t)ds.y * 16;
                for (int c = 0; c < 16; c++) {
                    uint4 v = xr[c];
                    float* q = sA + ln * LDW + c * 8;
                    atomicAdd(q + 0, u2f_lo(v.x)); atomicAdd(q + 1, u2f_hi(v.x));
                    atomicAdd(q + 2, u2f_lo(v.y)); atomicAdd(q + 3, u2f_hi(v.y));
                    atomicAdd(q + 4, u2f_lo(v.z)); atomicAdd(q + 5, u2f_hi(v.z));
                    atomicAdd(q + 6, u2f_lo(v.w)); atomicAdd(q + 7, u2f_hi(v.w));
                }
            }
        }
    }
    __syncthreads();

    // ---- phase 2: split-bf16 MFMA from LDS; wave pair per 16-node tile ----
    int lane = tid & 63;
    int wave = tid >> 6;       // 0..7
    int tile = wave >> 1;      // 0..3: node tile
    int half = wave & 1;       // 0..1: column half (64 cols)
    int ar = lane & 15;        // A row within tile
    int kg = lane >> 4;        // k-subchunk of 8
    const float* ap = sA + (tile * 16 + ar) * LDW + kg * 8;
    short8v ahi[4], alo[4];
#pragma unroll
    for (int ks = 0; ks < 4; ks++) {
#pragma unroll
        for (int j = 0; j < 8; j++) {
            float av = ap[ks * 32 + j];
            bf16_t h = f2bf(av);
            ahi[ks][j] = (short)h;
            alo[ks][j] = (short)f2bf(av - bf2f(h));
        }
    }

    f32x4 acc[4];
#pragma unroll
    for (int c = 0; c < 4; c++) acc[c] = (f32x4){0.f, 0.f, 0.f, 0.f};

    const short8v* Bh = (const short8v*)Wf;        // 2048 hi frags
    const short8v* Bl = Bh + 2048;                 // 2048 lo frags
#pragma unroll
    for (int ks = 0; ks < 4; ks++) {
#pragma unroll
        for (int c = 0; c < 4; c++) {
            int off = (ks * 8 + half * 4 + c) * 64 + lane;
            short8v wh = Bh[off];
            short8v wl = Bl[off];
            acc[c] = __builtin_amdgcn_mfma_f32_16x16x32_bf16(ahi[ks], wh, acc[c], 0, 0, 0);
            acc[c] = __builtin_amdgcn_mfma_f32_16x16x32_bf16(alo[ks], wh, acc[c], 0, 0, 0);
            acc[c] = __builtin_amdgcn_mfma_f32_16x16x32_bf16(ahi[ks], wl, acc[c], 0, 0, 0);
        }
    }

    // ---- epilogue: col = half*64 + c*16 + (lane&15), node = n0 + tile*16 + kg*4 + r ----
    int ocol = lane & 15;
#pragma unroll
    for (int r = 0; r < 4; r++) {
        int node = n0 + tile * 16 + kg * 4 + r;
        if (node >= nN) continue;
        float ri = rs_in[node];
        float ro = RELU_OUTSCALE ? rs_out[node] : 1.0f;
#pragma unroll
        for (int c = 0; c < 4; c++) {
            int col = half * 64 + c * 16 + ocol;
            float v = acc[c][r] * ri + bias[col];
            if (RELU_OUTSCALE) v = fmaxf(v, 0.0f) * ro;
            if (OUT_BF16) {
                ((bf16_t*)outp)[(size_t)node * D + col] = f2bf(v);
            } else {
                ((float*)outp)[(size_t)node * D + col] = v;
            }
        }
    }
}
#undef LDW

static inline size_t align16(size_t x) { return (x + 15) & ~(size_t)15; }

extern "C" void kernel_launch(void* const* d_in, const int* in_sizes, int n_in,
                              void* d_out, int out_size, void* d_ws, size_t ws_size,
                              hipStream_t stream) {
    const float* x   = (const float*)d_in[0];
    const int*   src = (const int*)d_in[1];
    const int*   dst = (const int*)d_in[2];
    const float* W1  = (const float*)d_in[3];
    const float* b1  = (const float*)d_in[4];
    const float* W2  = (const float*)d_in[5];
    const float* b2  = (const float*)d_in[6];
    float* out = (float*)d_out;

    char* p = (char*)d_ws;
    int*            cnt_s   = (int*)p;            p += align16(N_NODES * sizeof(int));
    int*            cnt_d   = (int*)p;            p += align16(N_NODES * sizeof(int));
    int*            ovf_cnt = (int*)p;            p += align16(16 * sizeof(int));
    int2*           ovf     = (int2*)p;           p += align16((size_t)OVF_CAP * sizeof(int2));
    unsigned short* bucket  = (unsigned short*)p; p += align16((size_t)N_NODES * CAP * sizeof(unsigned short));
    float*          rs_out  = (float*)p;          p += align16(N_NODES * sizeof(float));
    float*          rs_in   = (float*)p;          p += align16(N_NODES * sizeof(float));
    bf16_t*         Wf1     = (bf16_t*)p;         p += align16((size_t)2 * 2048 * 8 * sizeof(bf16_t));
    bf16_t*         Wf2     = (bf16_t*)p;         p += align16((size_t)2 * 2048 * 8 * sizeof(bf16_t));
    unsigned int*   H40     = (unsigned int*)p;   p += align16((size_t)B1 * BINS * sizeof(unsigned int));
    unsigned int*   OFF40   = (unsigned int*)p;   p += align16((size_t)B1 * BINS * sizeof(unsigned int));
    unsigned int*   binBase = (unsigned int*)p;   p += align16(BINS * sizeof(unsigned int));
    unsigned int*   binTot  = (unsigned int*)p;   p += align16(BINS * sizeof(unsigned int));
    unsigned int*   binned  = (unsigned int*)p;   p += align16((size_t)N_EDGES * sizeof(unsigned int));
    unsigned int*   SH      = (unsigned int*)p;   p += align16((size_t)B1 * NW * sizeof(unsigned int));
    bf16_t*         xs      = (bf16_t*)p;         p += align16((size_t)N_NODES * D * sizeof(bf16_t));
    bf16_t*         hs      = (bf16_t*)p;         // separate 12.8 MB buffer

    // weight hi/lo split into MFMA fragment layout (both layers, one tiny launch)
    wsplit_kernel<<<dim3(8, 2), 256, 0, stream>>>(W1, Wf1, W2, Wf2);

    // two-phase binned scatter (hist40 zeroes ovf_cnt; place40 folds sreduce)
    hist40_kernel<<<B1, 1024, 0, stream>>>(src, dst, H40, SH, ovf_cnt, N_EDGES);
    scan40_kernel<<<1, 64, 0, stream>>>(H40, OFF40, binBase, binTot);
    place40_kernel<<<B1, 1024, 0, stream>>>(src, dst, OFF40, binned, SH, cnt_s, N_EDGES);
    scatter2_kernel<<<BINS, 1024, 0, stream>>>(binned, binBase, binTot, bucket,
                                               cnt_d, ovf_cnt, ovf);

    // rs arrays + xs = bf16(x * rs_out), row-major
    prescale_kernel<<<(N_NODES + 7) / 8, 256, 0, stream>>>((const float4*)x, cnt_s, cnt_d,
                                                           rs_out, rs_in, (ushort4*)xs, N_NODES);

    int fgrid = (N_NODES + 63) / 64;   // 64 nodes per fused block

    // layer 1: hs = bf16( relu(rs_in * (gather(xs) @ W1) + b1) * rs_out )
    fused_layer_kernel<true, true><<<fgrid, 512, 0, stream>>>(
        (const uint4*)xs, cnt_d, bucket, ovf_cnt, ovf, rs_in, rs_out, Wf1, b1, hs, N_NODES);

    // layer 2: out = rs_in * (gather(hs) @ W2) + b2   (fp32 row-major)
    fused_layer_kernel<false, false><<<fgrid, 512, 0, stream>>>(
        (const uint4*)hs, cnt_d, bucket, ovf_cnt, ovf, rs_in, rs_out, Wf2, b2, out, N_NODES);
}